// Round 13
// baseline (152.207 us; speedup 1.0000x reference)
//
#include <hip/hip_runtime.h>
#include <math.h>

// Strict IEEE fp32, no FMA contraction: replicate CPU LAPACK rounding exactly
// (verified green: absmax 0.03125).
#pragma clang fp contract(off)

typedef float2 cplx;

__device__ __forceinline__ cplx cmk(float x, float y){ cplx r; r.x=x; r.y=y; return r; }
__device__ __forceinline__ cplx cadd(cplx a, cplx b){ return cmk(a.x+b.x, a.y+b.y); }
__device__ __forceinline__ cplx csub(cplx a, cplx b){ return cmk(a.x-b.x, a.y-b.y); }
__device__ __forceinline__ cplx cmul(cplx a, cplx b){ return cmk(a.x*b.x - a.y*b.y, a.x*b.y + a.y*b.x); }
__device__ __forceinline__ cplx conjc(cplx a){ return cmk(a.x, -a.y); }

__device__ __forceinline__ float fsign(float a, float b){
    float aa = fabsf(a);
    return (b >= 0.f) ? aa : -aa;
}

__device__ __forceinline__ float lapy2(float x, float y){
    float xa = fabsf(x), ya = fabsf(y);
    float w = fmaxf(xa, ya), z = fminf(xa, ya);
    if (z == 0.f) return w;
    float q = z / w;
    return w * sqrtf(1.f + q*q);
}

__device__ __forceinline__ float lapy3(float x, float y, float z){
    float xa = fabsf(x), ya = fabsf(y), za = fabsf(z);
    float w = fmaxf(fmaxf(xa, ya), za);
    if (w == 0.f) return xa + ya + za;
    float a = xa/w, b = ya/w, c = za/w;
    return w * sqrtf(a*a + b*b + c*c);
}

// SLADIV (LAPACK >= 3.5, Baudin-Smith)
__device__ __forceinline__ float sladiv2(float a, float b, float c, float d,
                                         float r, float t){
    if (r != 0.f) {
        float br = b*r;
        if (br != 0.f) return (a + br)*t;
        return a*t + (b*t)*r;
    }
    return (a + d*(b/c))*t;
}

__device__ __forceinline__ void sladiv1(float a, float b, float c, float d,
                                        float* p, float* q){
    float r = d / c;
    float t = 1.f / (c + d*r);
    *p = sladiv2(a, b, c, d, r, t);
    a = -a;
    *q = sladiv2(b, a, c, d, r, t);
}

__device__ __forceinline__ cplx ladiv(cplx x, cplx y){
    float p, q;
    if (fabsf(y.y) <= fabsf(y.x)) {
        sladiv1(x.x, x.y, y.x, y.y, &p, &q);
    } else {
        sladiv1(x.y, x.x, y.y, y.x, &p, &q);
        q = -q;
    }
    return cmk(p, q);
}

// SLARTG, LAPACK >= 3.10 convention
__device__ __forceinline__ void lartg(float f, float g, float* cs, float* sn, float* r)
{
    const float SAFMIN = 1.1754944e-38f;
    const float SAFMAX = 8.5070592e+37f;
    const float RTMIN  = 1.0842022e-19f;
    const float RTMAX  = 6.5249474e+18f;
    if (g == 0.f) { *cs = 1.f; *sn = 0.f; *r = f; }
    else if (f == 0.f) { *cs = 0.f; *sn = (g > 0.f) ? 1.f : -1.f; *r = fabsf(g); }
    else {
        float f1 = fabsf(f), g1 = fabsf(g);
        if (f1 > RTMIN && f1 < RTMAX && g1 > RTMIN && g1 < RTMAX) {
            float d = sqrtf(f*f + g*g);
            *cs = f1 / d;
            *r = (f >= 0.f) ? d : -d;
            *sn = g / *r;
        } else {
            float uu = fminf(SAFMAX, fmaxf(SAFMIN, fmaxf(f1, g1)));
            float fs = f/uu, gs = g/uu;
            float d = sqrtf(fs*fs + gs*gs);
            *cs = fabsf(fs)/d;
            *r = ((f >= 0.f) ? d : -d)*uu;
            *sn = g / *r;
        }
    }
}

// SLAEV2 (verbatim)
__device__ __forceinline__ void laev2(float a, float b, float c,
                                      float* rt1, float* rt2, float* cs1, float* sn1)
{
    float sm = a + c, df = a - c, adf = fabsf(df), tb = b + b, ab = fabsf(tb);
    float acmx, acmn;
    if (fabsf(a) > fabsf(c)) { acmx = a; acmn = c; } else { acmx = c; acmn = a; }
    float rt;
    if (adf > ab)      { float q = ab/adf; rt = adf*sqrtf(1.f + q*q); }
    else if (adf < ab) { float q = adf/ab; rt = ab*sqrtf(1.f + q*q); }
    else               { rt = ab*sqrtf(2.f); }
    int sgn1;
    if (sm < 0.f)      { *rt1 = 0.5f*(sm - rt); sgn1 = -1; *rt2 = (acmx / *rt1)*acmn - (b / *rt1)*b; }
    else if (sm > 0.f) { *rt1 = 0.5f*(sm + rt); sgn1 =  1; *rt2 = (acmx / *rt1)*acmn - (b / *rt1)*b; }
    else               { *rt1 = 0.5f*rt; *rt2 = -0.5f*rt; sgn1 = 1; }
    float cs; int sgn2;
    if (df >= 0.f) { cs = df + rt; sgn2 = 1; } else { cs = df - rt; sgn2 = -1; }
    float acs = fabsf(cs);
    if (acs > ab) {
        float ct = -tb/cs;
        *sn1 = 1.f/sqrtf(1.f + ct*ct);
        *cs1 = ct * (*sn1);
    } else {
        if (ab == 0.f) { *cs1 = 1.f; *sn1 = 0.f; }
        else {
            float tn = -cs/tb;
            *cs1 = 1.f/sqrtf(1.f + tn*tn);
            *sn1 = tn * (*cs1);
        }
    }
    if (sgn1 == sgn2) { float tn = *cs1; *cs1 = -(*sn1); *sn1 = tn; }
}

__device__ __forceinline__ constexpr int LT(int r, int c){ return r*(r+1)/2 + c; }

// ---- workspace layout (floats, planar [elem][gid]) ----
#define NBIN 4096
#define WS_W(k)    ((23+(k))*NBIN)     /* 16: final weights (kept at old offset) */

// ======== chetd2 step I — one bin per wave, lane-parallel BLAS2 ========
// Scalar parts (larfg, cdotc) are redundant across all 64 lanes (uniform);
// hemv row r -> lane r (each w8[r]'s reference addition order is an
// independent chain); her2 element (r,j) is written once -> lane r owns row r.
// Arithmetic sequences per stored value match the LAPACK reference exactly.
template<int I>
__device__ __forceinline__ void chetd2_wave_step(int tid, cplx* A, cplx* W,
                                                 cplx* Tau, float* Dd, float* Ee)
{
    cplx alpha = A[LT(I+1,I)];
    float xn2 = 0.f;
    #pragma unroll
    for (int k = I+2; k < 8; k++) { cplx v = A[LT(k,I)]; xn2 = xn2 + v.x*v.x; xn2 = xn2 + v.y*v.y; }
    float xnorm = sqrtf(xn2);
    cplx taui; float ei;
    if (xnorm == 0.f && alpha.y == 0.f) {
        taui = cmk(0.f, 0.f); ei = alpha.x;
    } else {
        float mag = lapy3(alpha.x, alpha.y, xnorm);
        float beta = (alpha.x >= 0.f) ? -mag : mag;
        taui = cmk((beta - alpha.x)/beta, -alpha.y/beta);
        cplx inv = ladiv(cmk(1.f,0.f), cmk(alpha.x - beta, alpha.y));
        if (tid >= I+2 && tid < 8) A[LT(tid,I)] = cmul(inv, A[LT(tid,I)]);   // CSCAL, lane k
        ei = beta;
    }
    __syncthreads();
    if (taui.x != 0.f || taui.y != 0.f) {          // uniform branch (redundant taui)
        // CHEMV: lane r computes w8[r] with the reference addition order:
        // j-ascending off-diag terms, then diagonal, then taui*temp2_r.
        if (tid >= I+1 && tid < 8) {
            const int r = tid;
            cplx w = cmk(0.f, 0.f);
            for (int j = I+1; j < r; j++) {
                cplx xj = (j == I+1) ? cmk(1.f,0.f) : A[LT(j,I)];
                cplx t1 = cmul(taui, xj);
                w = cadd(w, cmul(t1, A[LT(r,j)]));
            }
            cplx xr = (r == I+1) ? cmk(1.f,0.f) : A[LT(r,I)];
            cplx t1r = cmul(taui, xr);
            float dj = A[LT(r,r)].x;
            w.x = w.x + t1r.x*dj;
            w.y = w.y + t1r.y*dj;
            cplx t2 = cmk(0.f, 0.f);
            for (int rr = r+1; rr < 8; rr++)
                t2 = cadd(t2, cmul(conjc(A[LT(rr,r)]), A[LT(rr,I)]));
            w = cadd(w, cmul(taui, t2));
            W[r] = w;
        }
        __syncthreads();
        // CDOTC + alpha2: redundant on all lanes
        cplx dot = cmk(0.f, 0.f);
        #pragma unroll
        for (int r = I+1; r < 8; r++) {
            cplx v = (r == I+1) ? cmk(1.f,0.f) : A[LT(r,I)];
            dot = cadd(dot, cmul(conjc(W[r]), v));
        }
        cplx a2 = cmul(cmk(-0.5f*taui.x, -0.5f*taui.y), dot);
        __syncthreads();
        // CAXPY: lane r
        if (tid >= I+1 && tid < 8) {
            cplx v = (tid == I+1) ? cmk(1.f,0.f) : A[LT(tid,I)];
            W[tid] = cadd(W[tid], cmul(a2, v));
        }
        __syncthreads();
        // CHER2: lane r updates row r (each A(r,j) written once; two cadds in
        // reference order; diagonal uses the (p1.x + p2.x) grouped sum).
        if (tid >= I+1 && tid < 8) {
            const int r = tid;
            cplx xr = (r == I+1) ? cmk(1.f,0.f) : A[LT(r,I)];
            cplx yr = W[r];
            for (int j = I+1; j < r; j++) {
                cplx xj = (j == I+1) ? cmk(1.f,0.f) : A[LT(j,I)];
                cplx yj = W[j];
                cplx t1 = cmk(-yj.x, yj.y);
                cplx t2 = cmk(-xj.x, xj.y);
                cplx a = A[LT(r,j)];
                a = cadd(a, cmul(xr, t1));
                a = cadd(a, cmul(yr, t2));
                A[LT(r,j)] = a;
            }
            cplx t1 = cmk(-yr.x, yr.y);
            cplx t2 = cmk(-xr.x, xr.y);
            cplx p1 = cmul(xr, t1);
            cplx p2 = cmul(yr, t2);
            A[LT(r,r)] = cmk(A[LT(r,r)].x + (p1.x + p2.x), 0.f);
        }
    } else {
        if (tid == 0) A[LT(I+1,I+1)].y = 0.f;
    }
    __syncthreads();
    if (tid == 0) { Dd[I] = A[LT(I,I)].x; Ee[I] = ei; Tau[I] = taui; }
    __syncthreads();
}

// ======== cunm2r step I — redundant dot, lane-parallel update ========
template<int I>
__device__ __forceinline__ void unmqr_wave_step(int tid, const cplx* A,
                                                const cplx* Tau, cplx* U)
{
    cplx taui = Tau[I];
    if (taui.x != 0.f || taui.y != 0.f) {
        cplx dot = U[I+1];
        #pragma unroll
        for (int k = I+2; k < 8; k++) dot = cadd(dot, cmul(conjc(A[LT(k,I)]), U[k]));
        cplx td = cmul(taui, dot);
        __syncthreads();
        if (tid == I+1) U[tid] = csub(U[tid], td);
        if (tid >= I+2 && tid < 8) U[tid] = csub(U[tid], cmul(A[LT(tid,I)], td));
    }
    __syncthreads();
}

// ======== Cholesky step J — redundant diag, lane-parallel column ========
template<int J>
__device__ __forceinline__ void chol_wave_step(int tid, cplx* N)
{
    float sum = N[LT(J,J)].x;
    #pragma unroll
    for (int k = 0; k < J; k++) { cplx lv = N[LT(J,k)]; sum -= lv.x*lv.x + lv.y*lv.y; }
    float ljj = sqrtf(fmaxf(sum, 1e-30f));
    __syncthreads();
    if (tid == 0) N[LT(J,J)] = cmk(ljj, 0.f);
    if (tid > J && tid < 8) {
        cplx acc = N[LT(tid,J)];
        #pragma unroll
        for (int k = 0; k < J; k++) acc = csub(acc, cmul(N[LT(tid,k)], conjc(N[LT(J,k)])));
        N[LT(tid,J)] = cmk(acc.x/ljj, acc.y/ljj);
    }
    __syncthreads();
}

// ============ fused weights kernel: one bin per wave ============
__global__ __launch_bounds__(64) void mvdr_weights_wave(
    const float* __restrict__ ts_re, const float* __restrict__ ts_im,
    const float* __restrict__ ns_re, const float* __restrict__ ns_im,
    float* __restrict__ ws)
{
#pragma clang fp contract(off)
    const int tid = threadIdx.x;
    const int bin = blockIdx.x;
    const int b = bin >> 9, freq = bin & 511;
    const size_t tbase = (size_t)b*64*512 + freq;

    __shared__ cplx  Asm[36];   // target SCM lower-tri -> Householder V
    __shared__ cplx  Wsm[8];    // hemv work vector
    __shared__ cplx  Tsm[7];    // taus
    __shared__ float Dd[8];
    __shared__ float Ee[8];
    __shared__ float Zs[64];    // steqr Z, row-major; lane r owns row r
    __shared__ cplx  Usm[8];    // eigvec
    __shared__ cplx  Nsm[36];   // noise SCM -> chol L

    // ---- load target SCM lower triangle (cheevd 'L': diag imag ignored) ----
    if (tid < 36) {
        int r = 0;
        #pragma unroll
        for (int rr = 1; rr < 8; rr++) if (tid >= rr*(rr+1)/2) r = rr;
        int c = tid - r*(r+1)/2;
        float re = ts_re[tbase + (size_t)(r*8+c)*512];
        float im = (r==c) ? 0.f : ts_im[tbase + (size_t)(r*8+c)*512];
        Asm[tid] = cmk(re, im);
    }
    __syncthreads();

    // ---- chetd2 (lane-parallel) ----
    chetd2_wave_step<0>(tid, Asm, Wsm, Tsm, Dd, Ee);
    chetd2_wave_step<1>(tid, Asm, Wsm, Tsm, Dd, Ee);
    chetd2_wave_step<2>(tid, Asm, Wsm, Tsm, Dd, Ee);
    chetd2_wave_step<3>(tid, Asm, Wsm, Tsm, Dd, Ee);
    chetd2_wave_step<4>(tid, Asm, Wsm, Tsm, Dd, Ee);
    chetd2_wave_step<5>(tid, Asm, Wsm, Tsm, Dd, Ee);
    chetd2_wave_step<6>(tid, Asm, Wsm, Tsm, Dd, Ee);
    if (tid == 0) Dd[7] = Asm[LT(7,7)].x;
    if (tid < 8) {
        #pragma unroll
        for (int c = 0; c < 8; c++) Zs[tid*8 + c] = (tid == c) ? 1.f : 0.f;
    }
    __syncthreads();

#define D1(i)    Dd[(i)-1]
#define E1(i)    Ee[(i)-1]
    // ---- steqr (verbatim round-7 proven wave version) ----
    {
        const float EPS   = 5.9604645e-08f;
        const float EPS2  = 3.5527137e-15f;
        const float SAFMIN= 1.1754944e-38f;
        int l1 = 1, l = 0, lsv = 0, lend = 0, lendsv = 0, mm = 0, jtot = 0;
        float p, g, r_, c_, s_, f_, b_, rt1, rt2;

      L10:
        if (l1 > 8) goto Lsort;
        if (l1 > 1) { if (!tid) E1(l1-1) = 0.f; }
        mm = 8;
        if (l1 <= 7) {
            for (int m2 = l1; m2 <= 7; m2++) {
                float tst = fabsf(E1(m2));
                if (tst == 0.f) { mm = m2; goto L30; }
                if (tst <= (sqrtf(fabsf(D1(m2)))*sqrtf(fabsf(D1(m2+1))))*EPS) {
                    if (!tid) E1(m2) = 0.f;
                    mm = m2; goto L30;
                }
            }
            mm = 8;
        }
      L30:
        l = l1; lsv = l; lend = mm; lendsv = lend; l1 = mm + 1;
        if (lend == l) goto L10;
        {
            float an = 0.f;
            for (int ii = l; ii <= lend; ii++) an = fmaxf(an, fabsf(D1(ii)));
            for (int ii = l; ii <  lend; ii++) an = fmaxf(an, fabsf(E1(ii)));
            if (an == 0.f) goto L10;
        }
        if (fabsf(D1(lend)) < fabsf(D1(l))) { lend = lsv; l = lendsv; }

        if (lend > l) {
          L40:
            if (l != lend) {
                for (mm = l; mm <= lend-1; mm++) {
                    float tst = E1(mm)*E1(mm);
                    if (tst <= (EPS2*fabsf(D1(mm)))*fabsf(D1(mm+1)) + SAFMIN) goto L60;
                }
                mm = lend;
            } else mm = lend;
          L60:
            if (mm < lend) { if (!tid) E1(mm) = 0.f; }
            p = D1(l);
            if (mm == l) goto L80;
            if (mm == l+1) {
                laev2(D1(l), E1(l), D1(l+1), &rt1, &rt2, &c_, &s_);
                if (tid < 8) {
                    float t  = Zs[tid*8 + l];
                    float zl = Zs[tid*8 + l-1];
                    Zs[tid*8 + l]   = c_*t - s_*zl;
                    Zs[tid*8 + l-1] = s_*t + c_*zl;
                }
                if (!tid) { D1(l) = rt1; D1(l+1) = rt2; E1(l) = 0.f; }
                l += 2;
                if (l <= lend) goto L40;
                goto L140;
            }
            if (jtot == 240) goto L140;
            jtot++;
            g = (D1(l+1) - p) / (2.f*E1(l));
            r_ = lapy2(g, 1.f);
            g = D1(mm) - p + E1(l)/(g + fsign(r_, g));
            s_ = 1.f; c_ = 1.f; p = 0.f;
            for (int i2 = mm-1; i2 >= l; i2--) {
                f_ = s_*E1(i2); b_ = c_*E1(i2);
                lartg(g, f_, &c_, &s_, &r_);
                if (i2 != mm-1) { if (!tid) E1(i2+1) = r_; }
                g = D1(i2+1) - p;
                r_ = (D1(i2) - g)*s_ + 2.f*c_*b_;
                p = s_*r_;
                if (!tid) D1(i2+1) = g + p;
                g = c_*r_ - b_;
                if (tid < 8) {
                    float t  = Zs[tid*8 + i2];
                    float zj = Zs[tid*8 + i2-1];
                    Zs[tid*8 + i2]   = c_*t + s_*zj;
                    Zs[tid*8 + i2-1] = c_*zj - s_*t;
                }
            }
            if (!tid) { D1(l) = D1(l) - p; E1(l) = g; }
            goto L40;
          L80:
            if (!tid) D1(l) = p;
            l++;
            if (l <= lend) goto L40;
            goto L140;
        } else {
          L90:
            if (l != lend) {
                for (mm = l; mm >= lend+1; mm--) {
                    float tst = E1(mm-1)*E1(mm-1);
                    if (tst <= (EPS2*fabsf(D1(mm)))*fabsf(D1(mm-1)) + SAFMIN) goto L110;
                }
                mm = lend;
            } else mm = lend;
          L110:
            if (mm > lend) { if (!tid) E1(mm-1) = 0.f; }
            p = D1(l);
            if (mm == l) goto L130;
            if (mm == l-1) {
                laev2(D1(l-1), E1(l-1), D1(l), &rt1, &rt2, &c_, &s_);
                if (tid < 8) {
                    float t  = Zs[tid*8 + l-1];
                    float zl = Zs[tid*8 + l-2];
                    Zs[tid*8 + l-1] = c_*t - s_*zl;
                    Zs[tid*8 + l-2] = s_*t + c_*zl;
                }
                if (!tid) { D1(l-1) = rt1; D1(l) = rt2; E1(l-1) = 0.f; }
                l -= 2;
                if (l >= lend) goto L90;
                goto L140;
            }
            if (jtot == 240) goto L140;
            jtot++;
            g = (D1(l-1) - p)/(2.f*E1(l-1));
            r_ = lapy2(g, 1.f);
            g = D1(mm) - p + E1(l-1)/(g + fsign(r_, g));
            s_ = 1.f; c_ = 1.f; p = 0.f;
            for (int i2 = mm; i2 <= l-1; i2++) {
                f_ = s_*E1(i2); b_ = c_*E1(i2);
                lartg(g, f_, &c_, &s_, &r_);
                if (i2 != mm) { if (!tid) E1(i2-1) = r_; }
                g = D1(i2) - p;
                r_ = (D1(i2+1) - g)*s_ + 2.f*c_*b_;
                p = s_*r_;
                if (!tid) D1(i2) = g + p;
                g = c_*r_ - b_;
                if (tid < 8) {
                    float t  = Zs[tid*8 + i2];
                    float zj = Zs[tid*8 + i2-1];
                    Zs[tid*8 + i2]   = c_*t - s_*zj;
                    Zs[tid*8 + i2-1] = s_*t + c_*zj;
                }
            }
            if (!tid) { D1(l) = D1(l) - p; E1(l-1) = g; }
            goto L90;
          L130:
            if (!tid) D1(l) = p;
            l--;
            if (l >= lend) goto L90;
            goto L140;
        }
      L140:
        if (jtot < 240) goto L10;
      Lsort:
        for (int ii = 2; ii <= 8; ii++) {
            int i2 = ii-1, kk = i2;
            p = D1(i2);
            for (int j2 = ii; j2 <= 8; j2++) if (D1(j2) < p) { kk = j2; p = D1(j2); }
            if (kk != i2) {
                if (!tid) { D1(kk) = D1(i2); D1(i2) = p; }
                if (tid < 8) {
                    float t = Zs[tid*8 + i2-1];
                    Zs[tid*8 + i2-1] = Zs[tid*8 + kk-1];
                    Zs[tid*8 + kk-1] = t;
                }
            }
        }
    }
#undef D1
#undef E1

    if (tid < 8) Usm[tid] = cmk(Zs[tid*8 + 7], 0.f);
    __syncthreads();

    // ---- back-transform: atf = H(1)...H(7) * u ----
    unmqr_wave_step<6>(tid, Asm, Tsm, Usm);
    unmqr_wave_step<5>(tid, Asm, Tsm, Usm);
    unmqr_wave_step<4>(tid, Asm, Tsm, Usm);
    unmqr_wave_step<3>(tid, Asm, Tsm, Usm);
    unmqr_wave_step<2>(tid, Asm, Tsm, Usm);
    unmqr_wave_step<1>(tid, Asm, Tsm, Usm);
    unmqr_wave_step<0>(tid, Asm, Tsm, Usm);

    // ---- noise SCM lower triangle ----
    if (tid < 36) {
        int r = 0;
        #pragma unroll
        for (int rr = 1; rr < 8; rr++) if (tid >= rr*(rr+1)/2) r = rr;
        int c = tid - r*(r+1)/2;
        float re = ns_re[tbase + (size_t)(r*8+c)*512];
        float im = (r==c) ? 0.f : ns_im[tbase + (size_t)(r*8+c)*512];
        Nsm[tid] = cmk(re, im);
    }
    __syncthreads();

    // ---- Cholesky (lane-parallel columns) ----
    chol_wave_step<0>(tid, Nsm); chol_wave_step<1>(tid, Nsm);
    chol_wave_step<2>(tid, Nsm); chol_wave_step<3>(tid, Nsm);
    chol_wave_step<4>(tid, Nsm); chol_wave_step<5>(tid, Nsm);
    chol_wave_step<6>(tid, Nsm); chol_wave_step<7>(tid, Nsm);

    // ---- triangular solves + denominator: redundant on all lanes ----
    cplx u[8];
    #pragma unroll
    for (int r = 0; r < 8; r++) u[r] = Usm[r];
    cplx yv[8];
    #pragma unroll
    for (int r = 0; r < 8; r++) {
        cplx acc = u[r];
        for (int k = 0; k < r; k++) acc = csub(acc, cmul(Nsm[LT(r,k)], yv[k]));
        float inv = 1.f/Nsm[LT(r,r)].x;
        yv[r] = cmk(acc.x*inv, acc.y*inv);
    }
    cplx zv[8];
    #pragma unroll
    for (int r = 7; r >= 0; r--) {
        cplx acc = yv[r];
        for (int k = 7; k > r; k--) acc = csub(acc, cmul(conjc(Nsm[LT(k,r)]), zv[k]));
        float inv = 1.f/Nsm[LT(r,r)].x;
        zv[r] = cmk(acc.x*inv, acc.y*inv);
    }
    cplx den = cmk(0.f, 0.f);
    #pragma unroll
    for (int m3 = 0; m3 < 8; m3++) den = cadd(den, cmul(conjc(u[m3]), zv[m3]));
    if (tid == 0) {
        float dn = den.x*den.x + den.y*den.y;
        #pragma unroll
        for (int m3 = 0; m3 < 8; m3++) {
            float bfr = (zv[m3].x*den.x + zv[m3].y*den.y)/dn;
            float bfi = (zv[m3].y*den.x - zv[m3].x*den.y)/dn;
            ws[WS_W(2*m3)   + bin] = bfr;    // w = conj(bf)
            ws[WS_W(2*m3+1) + bin] = -bfi;
        }
    }
}

// ============ apply (round-12 green version; plateau ~95us @ ~3 TB/s) ============
__global__ __launch_bounds__(256) void mvdr_apply(
    const float* __restrict__ mix_re, const float* __restrict__ mix_im,
    const float* __restrict__ ws, float* __restrict__ out)
{
    const int bf = blockIdx.y;
    const int t = blockIdx.x*256 + threadIdx.x;
    const int b = bf >> 9, freq = bf & 511;
    if (t >= 1000) return;

    const size_t base = (((size_t)b*8)*512 + freq)*1000 + t;
    float xr[8], xi[8], wr[8], wi[8];
    #pragma unroll
    for (int m3 = 0; m3 < 8; m3++) {
        size_t idx = base + (size_t)m3*512*1000;
        xr[m3] = mix_re[idx];
        xi[m3] = mix_im[idx];
    }
    #pragma unroll
    for (int m3 = 0; m3 < 8; m3++) {
        wr[m3] = ws[WS_W(2*m3)   + bf];
        wi[m3] = ws[WS_W(2*m3+1) + bf];
    }
    float yr = 0.f;
    #pragma unroll
    for (int m3 = 0; m3 < 8; m3++)
        yr += wr[m3]*xr[m3] - wi[m3]*xi[m3];
    out[(size_t)bf*1000 + t] = yr;
}

extern "C" void kernel_launch(void* const* d_in, const int* in_sizes, int n_in,
                              void* d_out, int out_size, void* d_ws, size_t ws_size,
                              hipStream_t stream)
{
    (void)in_sizes; (void)n_in; (void)out_size; (void)ws_size;
    const float* mix_re = (const float*)d_in[0];
    const float* mix_im = (const float*)d_in[1];
    const float* ts_re  = (const float*)d_in[2];
    const float* ts_im  = (const float*)d_in[3];
    const float* ns_re  = (const float*)d_in[4];
    const float* ns_im  = (const float*)d_in[5];
    float* ws = (float*)d_ws;   // uses planes 23..38 (weights) = 639 KB

    mvdr_weights_wave<<<dim3(NBIN), dim3(64), 0, stream>>>(ts_re, ts_im, ns_re, ns_im, ws);
    mvdr_apply<<<dim3(4, NBIN), dim3(256), 0, stream>>>(mix_re, mix_im, ws, (float*)d_out);
}

// Round 14
// 144.648 us; speedup vs baseline: 1.0523x; 1.0523x over previous
//
#include <hip/hip_runtime.h>
#include <math.h>

// Strict IEEE fp32, no FMA contraction: replicate CPU LAPACK rounding exactly
// (verified green: absmax 0.03125).
#pragma clang fp contract(off)

typedef float2 cplx;

__device__ __forceinline__ cplx cmk(float x, float y){ cplx r; r.x=x; r.y=y; return r; }
__device__ __forceinline__ cplx cadd(cplx a, cplx b){ return cmk(a.x+b.x, a.y+b.y); }
__device__ __forceinline__ cplx csub(cplx a, cplx b){ return cmk(a.x-b.x, a.y-b.y); }
__device__ __forceinline__ cplx cmul(cplx a, cplx b){ return cmk(a.x*b.x - a.y*b.y, a.x*b.y + a.y*b.x); }
__device__ __forceinline__ cplx conjc(cplx a){ return cmk(a.x, -a.y); }

__device__ __forceinline__ float fsign(float a, float b){
    float aa = fabsf(a);
    return (b >= 0.f) ? aa : -aa;
}

__device__ __forceinline__ float lapy2(float x, float y){
    float xa = fabsf(x), ya = fabsf(y);
    float w = fmaxf(xa, ya), z = fminf(xa, ya);
    if (z == 0.f) return w;
    float q = z / w;
    return w * sqrtf(1.f + q*q);
}

__device__ __forceinline__ float lapy3(float x, float y, float z){
    float xa = fabsf(x), ya = fabsf(y), za = fabsf(z);
    float w = fmaxf(fmaxf(xa, ya), za);
    if (w == 0.f) return xa + ya + za;
    float a = xa/w, b = ya/w, c = za/w;
    return w * sqrtf(a*a + b*b + c*c);
}

// SLADIV (LAPACK >= 3.5, Baudin-Smith)
__device__ __forceinline__ float sladiv2(float a, float b, float c, float d,
                                         float r, float t){
    if (r != 0.f) {
        float br = b*r;
        if (br != 0.f) return (a + br)*t;
        return a*t + (b*t)*r;
    }
    return (a + d*(b/c))*t;
}

__device__ __forceinline__ void sladiv1(float a, float b, float c, float d,
                                        float* p, float* q){
    float r = d / c;
    float t = 1.f / (c + d*r);
    *p = sladiv2(a, b, c, d, r, t);
    a = -a;
    *q = sladiv2(b, a, c, d, r, t);
}

__device__ __forceinline__ cplx ladiv(cplx x, cplx y){
    float p, q;
    if (fabsf(y.y) <= fabsf(y.x)) {
        sladiv1(x.x, x.y, y.x, y.y, &p, &q);
    } else {
        sladiv1(x.y, x.x, y.y, y.x, &p, &q);
        q = -q;
    }
    return cmk(p, q);
}

// SLARTG, LAPACK >= 3.10 convention
__device__ __forceinline__ void lartg(float f, float g, float* cs, float* sn, float* r)
{
    const float SAFMIN = 1.1754944e-38f;
    const float SAFMAX = 8.5070592e+37f;
    const float RTMIN  = 1.0842022e-19f;
    const float RTMAX  = 6.5249474e+18f;
    if (g == 0.f) { *cs = 1.f; *sn = 0.f; *r = f; }
    else if (f == 0.f) { *cs = 0.f; *sn = (g > 0.f) ? 1.f : -1.f; *r = fabsf(g); }
    else {
        float f1 = fabsf(f), g1 = fabsf(g);
        if (f1 > RTMIN && f1 < RTMAX && g1 > RTMIN && g1 < RTMAX) {
            float d = sqrtf(f*f + g*g);
            *cs = f1 / d;
            *r = (f >= 0.f) ? d : -d;
            *sn = g / *r;
        } else {
            float uu = fminf(SAFMAX, fmaxf(SAFMIN, fmaxf(f1, g1)));
            float fs = f/uu, gs = g/uu;
            float d = sqrtf(fs*fs + gs*gs);
            *cs = fabsf(fs)/d;
            *r = ((f >= 0.f) ? d : -d)*uu;
            *sn = g / *r;
        }
    }
}

// SLAEV2 (verbatim)
__device__ __forceinline__ void laev2(float a, float b, float c,
                                      float* rt1, float* rt2, float* cs1, float* sn1)
{
    float sm = a + c, df = a - c, adf = fabsf(df), tb = b + b, ab = fabsf(tb);
    float acmx, acmn;
    if (fabsf(a) > fabsf(c)) { acmx = a; acmn = c; } else { acmx = c; acmn = a; }
    float rt;
    if (adf > ab)      { float q = ab/adf; rt = adf*sqrtf(1.f + q*q); }
    else if (adf < ab) { float q = adf/ab; rt = ab*sqrtf(1.f + q*q); }
    else               { rt = ab*sqrtf(2.f); }
    int sgn1;
    if (sm < 0.f)      { *rt1 = 0.5f*(sm - rt); sgn1 = -1; *rt2 = (acmx / *rt1)*acmn - (b / *rt1)*b; }
    else if (sm > 0.f) { *rt1 = 0.5f*(sm + rt); sgn1 =  1; *rt2 = (acmx / *rt1)*acmn - (b / *rt1)*b; }
    else               { *rt1 = 0.5f*rt; *rt2 = -0.5f*rt; sgn1 = 1; }
    float cs; int sgn2;
    if (df >= 0.f) { cs = df + rt; sgn2 = 1; } else { cs = df - rt; sgn2 = -1; }
    float acs = fabsf(cs);
    if (acs > ab) {
        float ct = -tb/cs;
        *sn1 = 1.f/sqrtf(1.f + ct*ct);
        *cs1 = ct * (*sn1);
    } else {
        if (ab == 0.f) { *cs1 = 1.f; *sn1 = 0.f; }
        else {
            float tn = -cs/tb;
            *cs1 = 1.f/sqrtf(1.f + tn*tn);
            *sn1 = tn * (*cs1);
        }
    }
    if (sgn1 == sgn2) { float tn = *cs1; *cs1 = -(*sn1); *sn1 = tn; }
}

__device__ __forceinline__ constexpr int LT(int r, int c){ return r*(r+1)/2 + c; }
__device__ __forceinline__ constexpr int VIDX(int I, int k){
    return (I*(13-I))/2 + (k - (I+2));
}

// ---- workspace layout (floats, planar [elem][gid]) ----
#define NBIN 4096
#define WS_DE(k)   ((k)*NBIN)          /* 15: d[0..7], e[0..6]        */
#define WS_U(k)    ((15+(k))*NBIN)     /* 8 : steqr eigvec col        */
#define WS_W(k)    ((23+(k))*NBIN)     /* 16: final weights           */
#define WS_V(k)    ((39+(k))*NBIN)     /* 42: Householder vectors     */
#define WS_TAU(k)  ((81+(k))*NBIN)     /* 14: taus                    */
#define WS_PLANES  95

// ================= GROUP (8 lanes per bin) PRIMITIVES =================
// Arithmetic chains identical to the r13 lane-parallel versions (verified
// bit-exact: absmax 0.03125). Barriers hoisted OUTSIDE the per-group
// conditionals so 8 groups per block can't deadlock.

template<int I>
__device__ __forceinline__ void chetd2_grp_step(int lane, cplx* A, cplx* W,
                                                cplx* Tau, float* Dd, float* Ee)
{
    cplx alpha = A[LT(I+1,I)];
    float xn2 = 0.f;
    #pragma unroll
    for (int k = I+2; k < 8; k++) { cplx v = A[LT(k,I)]; xn2 = xn2 + v.x*v.x; xn2 = xn2 + v.y*v.y; }
    float xnorm = sqrtf(xn2);
    cplx taui; float ei;
    bool doscal = !(xnorm == 0.f && alpha.y == 0.f);
    if (doscal) {
        float mag = lapy3(alpha.x, alpha.y, xnorm);
        float beta = (alpha.x >= 0.f) ? -mag : mag;
        taui = cmk((beta - alpha.x)/beta, -alpha.y/beta);
        cplx inv = ladiv(cmk(1.f,0.f), cmk(alpha.x - beta, alpha.y));
        if (lane >= I+2) A[LT(lane,I)] = cmul(inv, A[LT(lane,I)]);   // CSCAL
        ei = beta;
    } else {
        taui = cmk(0.f,0.f); ei = alpha.x;
    }
    __syncthreads();
    bool has = (taui.x != 0.f || taui.y != 0.f);
    // CHEMV: lane r computes w(r) in the reference addition order
    if (has && lane >= I+1) {
        const int r = lane;
        cplx w = cmk(0.f,0.f);
        for (int j = I+1; j < r; j++) {
            cplx xj = (j == I+1) ? cmk(1.f,0.f) : A[LT(j,I)];
            cplx t1 = cmul(taui, xj);
            w = cadd(w, cmul(t1, A[LT(r,j)]));
        }
        cplx xr = (r == I+1) ? cmk(1.f,0.f) : A[LT(r,I)];
        cplx t1r = cmul(taui, xr);
        float dj = A[LT(r,r)].x;
        w.x = w.x + t1r.x*dj;
        w.y = w.y + t1r.y*dj;
        cplx t2 = cmk(0.f,0.f);
        for (int rr = r+1; rr < 8; rr++)
            t2 = cadd(t2, cmul(conjc(A[LT(rr,r)]), A[LT(rr,I)]));
        w = cadd(w, cmul(taui, t2));
        W[r] = w;
    }
    __syncthreads();
    cplx a2 = cmk(0.f,0.f);
    if (has) {
        cplx dot = cmk(0.f,0.f);
        #pragma unroll
        for (int r = I+1; r < 8; r++) {
            cplx v = (r == I+1) ? cmk(1.f,0.f) : A[LT(r,I)];
            dot = cadd(dot, cmul(conjc(W[r]), v));
        }
        a2 = cmul(cmk(-0.5f*taui.x, -0.5f*taui.y), dot);
    }
    __syncthreads();
    if (has && lane >= I+1) {
        cplx v = (lane == I+1) ? cmk(1.f,0.f) : A[LT(lane,I)];
        W[lane] = cadd(W[lane], cmul(a2, v));
    }
    __syncthreads();
    // CHER2: lane r updates row r (each element written once, ref order)
    if (has && lane >= I+1) {
        const int r = lane;
        cplx xr = (r == I+1) ? cmk(1.f,0.f) : A[LT(r,I)];
        cplx yr = W[r];
        for (int j = I+1; j < r; j++) {
            cplx xj = (j == I+1) ? cmk(1.f,0.f) : A[LT(j,I)];
            cplx yj = W[j];
            cplx t1 = cmk(-yj.x, yj.y);
            cplx t2 = cmk(-xj.x, xj.y);
            cplx a = A[LT(r,j)];
            a = cadd(a, cmul(xr, t1));
            a = cadd(a, cmul(yr, t2));
            A[LT(r,j)] = a;
        }
        cplx t1 = cmk(-yr.x, yr.y);
        cplx t2 = cmk(-xr.x, xr.y);
        cplx p1 = cmul(xr, t1);
        cplx p2 = cmul(yr, t2);
        A[LT(r,r)] = cmk(A[LT(r,r)].x + (p1.x + p2.x), 0.f);
    }
    if (!has && lane == 0) A[LT(I+1,I+1)].y = 0.f;
    __syncthreads();
    if (lane == 0) { Dd[I] = A[LT(I,I)].x; Ee[I] = ei; Tau[I] = taui; }
    __syncthreads();
}

template<int I>
__device__ __forceinline__ void unmqr_grp_step(int lane, const cplx* VT,
                                               const cplx* Tau, cplx* U)
{
    cplx taui = Tau[I];
    bool has = (taui.x != 0.f || taui.y != 0.f);
    cplx td = cmk(0.f,0.f);
    if (has) {
        cplx dot = U[I+1];
        #pragma unroll
        for (int k = I+2; k < 8; k++) dot = cadd(dot, cmul(conjc(VT[VIDX(I,k)]), U[k]));
        td = cmul(taui, dot);
    }
    __syncthreads();
    if (has) {
        if (lane == I+1) U[lane] = csub(U[lane], td);
        if (lane >= I+2) U[lane] = csub(U[lane], cmul(VT[VIDX(I,lane)], td));
    }
    __syncthreads();
}

template<int J>
__device__ __forceinline__ void chol_grp_step(int lane, cplx* N)
{
    float sum = N[LT(J,J)].x;
    #pragma unroll
    for (int k = 0; k < J; k++) { cplx lv = N[LT(J,k)]; sum -= lv.x*lv.x + lv.y*lv.y; }
    float ljj = sqrtf(fmaxf(sum, 1e-30f));
    __syncthreads();
    if (lane == 0) N[LT(J,J)] = cmk(ljj, 0.f);
    if (lane > J) {
        cplx acc = N[LT(lane,J)];
        #pragma unroll
        for (int k = 0; k < J; k++) acc = csub(acc, cmul(N[LT(lane,k)], conjc(N[LT(J,k)])));
        N[LT(lane,J)] = cmk(acc.x/ljj, acc.y/ljj);
    }
    __syncthreads();
}

// ============ k1 (fast): chetd2, 8 bins/block x 8 lanes, 512 blocks ============
__global__ __launch_bounds__(64) void k1_tridiag_grp(
    const float* __restrict__ ts_re, const float* __restrict__ ts_im,
    float* __restrict__ ws)
{
#pragma clang fp contract(off)
    const int tid = threadIdx.x;
    const int g = tid >> 3, lane = tid & 7;
    const int bin = blockIdx.x*8 + g;
    const int b = bin >> 9, freq = bin & 511;
    const size_t tbase = (size_t)b*64*512 + freq;

    __shared__ cplx  Asm[8*36];
    __shared__ cplx  Wsm[8*8];
    __shared__ cplx  Tsm[8*7];
    __shared__ float Dds[8*8];
    __shared__ float Ees[8*7];
    cplx* A = Asm + g*36; cplx* W = Wsm + g*8; cplx* Tau = Tsm + g*7;
    float* Dd = Dds + g*8; float* Ee = Ees + g*7;

    for (int t = lane; t < 36; t += 8) {
        int r = 0;
        #pragma unroll
        for (int rr = 1; rr < 8; rr++) if (t >= rr*(rr+1)/2) r = rr;
        int c = t - r*(r+1)/2;
        float re = ts_re[tbase + (size_t)(r*8+c)*512];
        float im = (r==c) ? 0.f : ts_im[tbase + (size_t)(r*8+c)*512];
        A[t] = cmk(re, im);
    }
    __syncthreads();

    chetd2_grp_step<0>(lane, A, W, Tau, Dd, Ee);
    chetd2_grp_step<1>(lane, A, W, Tau, Dd, Ee);
    chetd2_grp_step<2>(lane, A, W, Tau, Dd, Ee);
    chetd2_grp_step<3>(lane, A, W, Tau, Dd, Ee);
    chetd2_grp_step<4>(lane, A, W, Tau, Dd, Ee);
    chetd2_grp_step<5>(lane, A, W, Tau, Dd, Ee);
    chetd2_grp_step<6>(lane, A, W, Tau, Dd, Ee);
    if (lane == 0) Dd[7] = A[LT(7,7)].x;
    __syncthreads();

    ws[WS_DE(lane) + bin] = Dd[lane];
    if (lane < 7) ws[WS_DE(8+lane) + bin] = Ee[lane];
    #pragma unroll
    for (int I = 0; I < 7; I++) {
        if (lane >= I+2) {
            ws[WS_V(2*VIDX(I,lane))   + bin] = A[LT(lane,I)].x;
            ws[WS_V(2*VIDX(I,lane)+1) + bin] = A[LT(lane,I)].y;
        }
    }
    if (lane < 7) {
        ws[WS_TAU(2*lane)   + bin] = Tau[lane].x;
        ws[WS_TAU(2*lane+1) + bin] = Tau[lane].y;
    }
}

// ============ k2: steqr — one bin per wave (verbatim, proven ~10us) ============
__global__ __launch_bounds__(64) void k2_steqr(float* __restrict__ ws)
{
#pragma clang fp contract(off)
    const int tid = threadIdx.x;
    const int bin = blockIdx.x;

    __shared__ float Dd[8];
    __shared__ float Ee[8];
    __shared__ float Zs[64];

#define D1(i)    Dd[(i)-1]
#define E1(i)    Ee[(i)-1]

    if (tid < 8) {
        Dd[tid] = ws[WS_DE(tid) + bin];
        if (tid < 7) Ee[tid] = ws[WS_DE(8+tid) + bin];
        #pragma unroll
        for (int c = 0; c < 8; c++) Zs[tid*8 + c] = (tid == c) ? 1.f : 0.f;
    }
    __syncthreads();

    {
        const float EPS   = 5.9604645e-08f;
        const float EPS2  = 3.5527137e-15f;
        const float SAFMIN= 1.1754944e-38f;
        int l1 = 1, l = 0, lsv = 0, lend = 0, lendsv = 0, mm = 0, jtot = 0;
        float p, g, r_, c_, s_, f_, b_, rt1, rt2;

      L10:
        if (l1 > 8) goto Lsort;
        if (l1 > 1) { if (!tid) E1(l1-1) = 0.f; }
        mm = 8;
        if (l1 <= 7) {
            for (int m2 = l1; m2 <= 7; m2++) {
                float tst = fabsf(E1(m2));
                if (tst == 0.f) { mm = m2; goto L30; }
                if (tst <= (sqrtf(fabsf(D1(m2)))*sqrtf(fabsf(D1(m2+1))))*EPS) {
                    if (!tid) E1(m2) = 0.f;
                    mm = m2; goto L30;
                }
            }
            mm = 8;
        }
      L30:
        l = l1; lsv = l; lend = mm; lendsv = lend; l1 = mm + 1;
        if (lend == l) goto L10;
        {
            float an = 0.f;
            for (int ii = l; ii <= lend; ii++) an = fmaxf(an, fabsf(D1(ii)));
            for (int ii = l; ii <  lend; ii++) an = fmaxf(an, fabsf(E1(ii)));
            if (an == 0.f) goto L10;
        }
        if (fabsf(D1(lend)) < fabsf(D1(l))) { lend = lsv; l = lendsv; }

        if (lend > l) {
          L40:
            if (l != lend) {
                for (mm = l; mm <= lend-1; mm++) {
                    float tst = E1(mm)*E1(mm);
                    if (tst <= (EPS2*fabsf(D1(mm)))*fabsf(D1(mm+1)) + SAFMIN) goto L60;
                }
                mm = lend;
            } else mm = lend;
          L60:
            if (mm < lend) { if (!tid) E1(mm) = 0.f; }
            p = D1(l);
            if (mm == l) goto L80;
            if (mm == l+1) {
                laev2(D1(l), E1(l), D1(l+1), &rt1, &rt2, &c_, &s_);
                if (tid < 8) {
                    float t  = Zs[tid*8 + l];
                    float zl = Zs[tid*8 + l-1];
                    Zs[tid*8 + l]   = c_*t - s_*zl;
                    Zs[tid*8 + l-1] = s_*t + c_*zl;
                }
                if (!tid) { D1(l) = rt1; D1(l+1) = rt2; E1(l) = 0.f; }
                l += 2;
                if (l <= lend) goto L40;
                goto L140;
            }
            if (jtot == 240) goto L140;
            jtot++;
            g = (D1(l+1) - p) / (2.f*E1(l));
            r_ = lapy2(g, 1.f);
            g = D1(mm) - p + E1(l)/(g + fsign(r_, g));
            s_ = 1.f; c_ = 1.f; p = 0.f;
            for (int i2 = mm-1; i2 >= l; i2--) {
                f_ = s_*E1(i2); b_ = c_*E1(i2);
                lartg(g, f_, &c_, &s_, &r_);
                if (i2 != mm-1) { if (!tid) E1(i2+1) = r_; }
                g = D1(i2+1) - p;
                r_ = (D1(i2) - g)*s_ + 2.f*c_*b_;
                p = s_*r_;
                if (!tid) D1(i2+1) = g + p;
                g = c_*r_ - b_;
                if (tid < 8) {
                    float t  = Zs[tid*8 + i2];
                    float zj = Zs[tid*8 + i2-1];
                    Zs[tid*8 + i2]   = c_*t + s_*zj;
                    Zs[tid*8 + i2-1] = c_*zj - s_*t;
                }
            }
            if (!tid) { D1(l) = D1(l) - p; E1(l) = g; }
            goto L40;
          L80:
            if (!tid) D1(l) = p;
            l++;
            if (l <= lend) goto L40;
            goto L140;
        } else {
          L90:
            if (l != lend) {
                for (mm = l; mm >= lend+1; mm--) {
                    float tst = E1(mm-1)*E1(mm-1);
                    if (tst <= (EPS2*fabsf(D1(mm)))*fabsf(D1(mm-1)) + SAFMIN) goto L110;
                }
                mm = lend;
            } else mm = lend;
          L110:
            if (mm > lend) { if (!tid) E1(mm-1) = 0.f; }
            p = D1(l);
            if (mm == l) goto L130;
            if (mm == l-1) {
                laev2(D1(l-1), E1(l-1), D1(l), &rt1, &rt2, &c_, &s_);
                if (tid < 8) {
                    float t  = Zs[tid*8 + l-1];
                    float zl = Zs[tid*8 + l-2];
                    Zs[tid*8 + l-1] = c_*t - s_*zl;
                    Zs[tid*8 + l-2] = s_*t + c_*zl;
                }
                if (!tid) { D1(l-1) = rt1; D1(l) = rt2; E1(l-1) = 0.f; }
                l -= 2;
                if (l >= lend) goto L90;
                goto L140;
            }
            if (jtot == 240) goto L140;
            jtot++;
            g = (D1(l-1) - p)/(2.f*E1(l-1));
            r_ = lapy2(g, 1.f);
            g = D1(mm) - p + E1(l-1)/(g + fsign(r_, g));
            s_ = 1.f; c_ = 1.f; p = 0.f;
            for (int i2 = mm; i2 <= l-1; i2++) {
                f_ = s_*E1(i2); b_ = c_*E1(i2);
                lartg(g, f_, &c_, &s_, &r_);
                if (i2 != mm) { if (!tid) E1(i2-1) = r_; }
                g = D1(i2) - p;
                r_ = (D1(i2+1) - g)*s_ + 2.f*c_*b_;
                p = s_*r_;
                if (!tid) D1(i2) = g + p;
                g = c_*r_ - b_;
                if (tid < 8) {
                    float t  = Zs[tid*8 + i2];
                    float zj = Zs[tid*8 + i2-1];
                    Zs[tid*8 + i2]   = c_*t - s_*zj;
                    Zs[tid*8 + i2-1] = s_*t + c_*zj;
                }
            }
            if (!tid) { D1(l) = D1(l) - p; E1(l-1) = g; }
            goto L90;
          L130:
            if (!tid) D1(l) = p;
            l--;
            if (l >= lend) goto L90;
            goto L140;
        }
      L140:
        if (jtot < 240) goto L10;
      Lsort:
        for (int ii = 2; ii <= 8; ii++) {
            int i2 = ii-1, kk = i2;
            p = D1(i2);
            for (int j2 = ii; j2 <= 8; j2++) if (D1(j2) < p) { kk = j2; p = D1(j2); }
            if (kk != i2) {
                if (!tid) { D1(kk) = D1(i2); D1(i2) = p; }
                if (tid < 8) {
                    float t = Zs[tid*8 + i2-1];
                    Zs[tid*8 + i2-1] = Zs[tid*8 + kk-1];
                    Zs[tid*8 + kk-1] = t;
                }
            }
        }
    }

    if (tid < 8) ws[WS_U(tid) + bin] = Zs[tid*8 + 7];
#undef D1
#undef E1
}

// ============ k3 (fast): unmqr + chol + solve, 8 bins/block x 8 lanes ============
__global__ __launch_bounds__(64) void k3_solve_grp(
    const float* __restrict__ ns_re, const float* __restrict__ ns_im,
    float* __restrict__ ws)
{
#pragma clang fp contract(off)
    const int tid = threadIdx.x;
    const int g = tid >> 3, lane = tid & 7;
    const int bin = blockIdx.x*8 + g;
    const int b = bin >> 9, freq = bin & 511;
    const size_t tbase = (size_t)b*64*512 + freq;

    __shared__ cplx VTs[8*21];
    __shared__ cplx Tsm[8*7];
    __shared__ cplx Usm[8*8];
    __shared__ cplx Nsm[8*36];
    cplx* VT = VTs + g*21; cplx* Tau = Tsm + g*7; cplx* U = Usm + g*8; cplx* N = Nsm + g*36;

    for (int t = lane; t < 21; t += 8)
        VT[t] = cmk(ws[WS_V(2*t) + bin], ws[WS_V(2*t+1) + bin]);
    if (lane < 7)
        Tau[lane] = cmk(ws[WS_TAU(2*lane) + bin], ws[WS_TAU(2*lane+1) + bin]);
    U[lane] = cmk(ws[WS_U(lane) + bin], 0.f);
    for (int t = lane; t < 36; t += 8) {
        int r = 0;
        #pragma unroll
        for (int rr = 1; rr < 8; rr++) if (t >= rr*(rr+1)/2) r = rr;
        int c = t - r*(r+1)/2;
        float re = ns_re[tbase + (size_t)(r*8+c)*512];
        float im = (r==c) ? 0.f : ns_im[tbase + (size_t)(r*8+c)*512];
        N[t] = cmk(re, im);
    }
    __syncthreads();

    unmqr_grp_step<6>(lane, VT, Tau, U);
    unmqr_grp_step<5>(lane, VT, Tau, U);
    unmqr_grp_step<4>(lane, VT, Tau, U);
    unmqr_grp_step<3>(lane, VT, Tau, U);
    unmqr_grp_step<2>(lane, VT, Tau, U);
    unmqr_grp_step<1>(lane, VT, Tau, U);
    unmqr_grp_step<0>(lane, VT, Tau, U);

    chol_grp_step<0>(lane, N); chol_grp_step<1>(lane, N);
    chol_grp_step<2>(lane, N); chol_grp_step<3>(lane, N);
    chol_grp_step<4>(lane, N); chol_grp_step<5>(lane, N);
    chol_grp_step<6>(lane, N); chol_grp_step<7>(lane, N);

    // triangular solves + denominator: redundant per lane (identical chains)
    cplx u[8];
    #pragma unroll
    for (int r = 0; r < 8; r++) u[r] = U[r];
    cplx yv[8];
    #pragma unroll
    for (int r = 0; r < 8; r++) {
        cplx acc = u[r];
        for (int k = 0; k < r; k++) acc = csub(acc, cmul(N[LT(r,k)], yv[k]));
        float inv = 1.f/N[LT(r,r)].x;
        yv[r] = cmk(acc.x*inv, acc.y*inv);
    }
    cplx zv[8];
    #pragma unroll
    for (int r = 7; r >= 0; r--) {
        cplx acc = yv[r];
        for (int k = 7; k > r; k--) acc = csub(acc, cmul(conjc(N[LT(k,r)]), zv[k]));
        float inv = 1.f/N[LT(r,r)].x;
        zv[r] = cmk(acc.x*inv, acc.y*inv);
    }
    cplx den = cmk(0.f, 0.f);
    #pragma unroll
    for (int m3 = 0; m3 < 8; m3++) den = cadd(den, cmul(conjc(u[m3]), zv[m3]));
    float dn = den.x*den.x + den.y*den.y;
    #pragma unroll
    for (int m3 = 0; m3 < 8; m3++) {
        if (m3 == lane) {   // static index into zv; lane m3 stores its pair
            float bfr = (zv[m3].x*den.x + zv[m3].y*den.y)/dn;
            float bfi = (zv[m3].y*den.x - zv[m3].x*den.y)/dn;
            ws[WS_W(2*m3)   + bin] = bfr;    // w = conj(bf)
            ws[WS_W(2*m3+1) + bin] = -bfi;
        }
    }
}

// ================= FALLBACK (per-thread, r12-verified) =================
template<int I>
__device__ __forceinline__ void chetd2_step(cplx* AT, cplx* tau, float* dreg, float* ereg)
{
    cplx alpha = AT[LT(I+1,I)];
    float xn2 = 0.f;
    #pragma unroll
    for (int k = I+2; k < 8; k++) { cplx v = AT[LT(k,I)]; xn2 = xn2 + v.x*v.x; xn2 = xn2 + v.y*v.y; }
    float xnorm = sqrtf(xn2);
    cplx taui; float ei;
    if (xnorm == 0.f && alpha.y == 0.f) {
        taui = cmk(0.f, 0.f); ei = alpha.x;
    } else {
        float mag = lapy3(alpha.x, alpha.y, xnorm);
        float beta = (alpha.x >= 0.f) ? -mag : mag;
        taui = cmk((beta - alpha.x)/beta, -alpha.y/beta);
        cplx inv = ladiv(cmk(1.f,0.f), cmk(alpha.x - beta, alpha.y));
        #pragma unroll
        for (int k = I+2; k < 8; k++) AT[LT(k,I)] = cmul(inv, AT[LT(k,I)]);
        ei = beta;
    }
    if (taui.x != 0.f || taui.y != 0.f) {
        cplx w8[8];
        #pragma unroll
        for (int r = I+1; r < 8; r++) w8[r] = cmk(0.f, 0.f);
        #pragma unroll
        for (int j = I+1; j < 8; j++) {
            cplx xj = (j == I+1) ? cmk(1.f,0.f) : AT[LT(j,I)];
            cplx temp1 = cmul(taui, xj);
            cplx temp2 = cmk(0.f, 0.f);
            float dj = AT[LT(j,j)].x;
            w8[j].x = w8[j].x + temp1.x*dj;
            w8[j].y = w8[j].y + temp1.y*dj;
            #pragma unroll
            for (int r = j+1; r < 8; r++) {
                cplx arj = AT[LT(r,j)];
                cplx xr  = AT[LT(r,I)];
                w8[r] = cadd(w8[r], cmul(temp1, arj));
                temp2 = cadd(temp2, cmul(conjc(arj), xr));
            }
            w8[j] = cadd(w8[j], cmul(taui, temp2));
        }
        cplx dot = cmk(0.f,0.f);
        #pragma unroll
        for (int r = I+1; r < 8; r++) {
            cplx v = (r == I+1) ? cmk(1.f,0.f) : AT[LT(r,I)];
            dot = cadd(dot, cmul(conjc(w8[r]), v));
        }
        cplx a2 = cmul(cmk(-0.5f*taui.x, -0.5f*taui.y), dot);
        #pragma unroll
        for (int r = I+1; r < 8; r++) {
            cplx v = (r == I+1) ? cmk(1.f,0.f) : AT[LT(r,I)];
            w8[r] = cadd(w8[r], cmul(a2, v));
        }
        #pragma unroll
        for (int j = I+1; j < 8; j++) {
            cplx xj = (j == I+1) ? cmk(1.f,0.f) : AT[LT(j,I)];
            cplx yj = w8[j];
            cplx temp1 = cmk(-yj.x, yj.y);
            cplx temp2 = cmk(-xj.x, xj.y);
            cplx p1 = cmul(xj, temp1);
            cplx p2 = cmul(yj, temp2);
            AT[LT(j,j)] = cmk(AT[LT(j,j)].x + (p1.x + p2.x), 0.f);
            #pragma unroll
            for (int r = j+1; r < 8; r++) {
                cplx xr = AT[LT(r,I)];
                cplx yr = w8[r];
                cplx a = AT[LT(r,j)];
                a = cadd(a, cmul(xr, temp1));
                a = cadd(a, cmul(yr, temp2));
                AT[LT(r,j)] = a;
            }
        }
    } else {
        AT[LT(I+1,I+1)].y = 0.f;
    }
    dreg[I] = AT[LT(I,I)].x;
    ereg[I] = ei;
    tau[I] = taui;
}

__device__ __forceinline__ void chetd2_full(const float* ts_re, const float* ts_im,
                                            size_t tbase, cplx* AT, cplx* tau,
                                            float* dreg, float* ereg)
{
    #pragma unroll
    for (int r = 0; r < 8; r++)
        #pragma unroll
        for (int c2 = 0; c2 <= r; c2++) {
            float re = ts_re[tbase + (size_t)(r*8+c2)*512];
            float im = (r==c2) ? 0.f : ts_im[tbase + (size_t)(r*8+c2)*512];
            AT[LT(r,c2)] = cmk(re, im);
        }
    chetd2_step<0>(AT, tau, dreg, ereg);
    chetd2_step<1>(AT, tau, dreg, ereg);
    chetd2_step<2>(AT, tau, dreg, ereg);
    chetd2_step<3>(AT, tau, dreg, ereg);
    chetd2_step<4>(AT, tau, dreg, ereg);
    chetd2_step<5>(AT, tau, dreg, ereg);
    chetd2_step<6>(AT, tau, dreg, ereg);
    dreg[7] = AT[LT(7,7)].x;
}

template<int I>
__device__ __forceinline__ void unmqr_step(const cplx* AT, const cplx* tau, cplx* u)
{
    cplx taui = tau[I];
    if (taui.x != 0.f || taui.y != 0.f) {
        cplx dot = u[I+1];
        #pragma unroll
        for (int k = I+2; k < 8; k++) dot = cadd(dot, cmul(conjc(AT[LT(k,I)]), u[k]));
        cplx td = cmul(taui, dot);
        u[I+1] = csub(u[I+1], td);
        #pragma unroll
        for (int k = I+2; k < 8; k++) u[k] = csub(u[k], cmul(AT[LT(k,I)], td));
    }
}

template<int J>
__device__ __forceinline__ void chol_step(cplx* NT)
{
    float sum = NT[LT(J,J)].x;
    #pragma unroll
    for (int k = 0; k < J; k++) { cplx lv = NT[LT(J,k)]; sum -= lv.x*lv.x + lv.y*lv.y; }
    float ljj = sqrtf(fmaxf(sum, 1e-30f));
    NT[LT(J,J)] = cmk(ljj, 0.f);
    #pragma unroll
    for (int r = J+1; r < 8; r++) {
        cplx acc = NT[LT(r,J)];
        #pragma unroll
        for (int k = 0; k < J; k++) acc = csub(acc, cmul(NT[LT(r,k)], conjc(NT[LT(J,k)])));
        NT[LT(r,J)] = cmk(acc.x/ljj, acc.y/ljj);
    }
}

__global__ __launch_bounds__(64) void k1_tridiag_slow(
    const float* __restrict__ ts_re, const float* __restrict__ ts_im,
    float* __restrict__ ws)
{
#pragma clang fp contract(off)
    const int gid = blockIdx.x*64 + threadIdx.x;
    const int b = gid >> 9, freq = gid & 511;
    const size_t tbase = (size_t)b*64*512 + freq;
    cplx AT[36], tau[7];
    float dreg[8], ereg[7];
    chetd2_full(ts_re, ts_im, tbase, AT, tau, dreg, ereg);
    #pragma unroll
    for (int k = 0; k < 8; k++) ws[WS_DE(k) + gid] = dreg[k];
    #pragma unroll
    for (int k = 0; k < 7; k++) ws[WS_DE(8+k) + gid] = ereg[k];
}

__global__ __launch_bounds__(64) void k3_solve_slow(
    const float* __restrict__ ts_re, const float* __restrict__ ts_im,
    const float* __restrict__ ns_re, const float* __restrict__ ns_im,
    float* __restrict__ ws)
{
#pragma clang fp contract(off)
    const int gid = blockIdx.x*64 + threadIdx.x;
    const int b = gid >> 9, freq = gid & 511;
    const size_t tbase = (size_t)b*64*512 + freq;

    cplx AT[36], tau[7];
    float dreg[8], ereg[7];
    chetd2_full(ts_re, ts_im, tbase, AT, tau, dreg, ereg);

    cplx u[8];
    #pragma unroll
    for (int r = 0; r < 8; r++) u[r] = cmk(ws[WS_U(r) + gid], 0.f);
    unmqr_step<6>(AT, tau, u);
    unmqr_step<5>(AT, tau, u);
    unmqr_step<4>(AT, tau, u);
    unmqr_step<3>(AT, tau, u);
    unmqr_step<2>(AT, tau, u);
    unmqr_step<1>(AT, tau, u);
    unmqr_step<0>(AT, tau, u);

    cplx NT[36];
    #pragma unroll
    for (int r = 0; r < 8; r++)
        #pragma unroll
        for (int c2 = 0; c2 <= r; c2++) {
            float re = ns_re[tbase + (size_t)(r*8+c2)*512];
            float im = (r==c2) ? 0.f : ns_im[tbase + (size_t)(r*8+c2)*512];
            NT[LT(r,c2)] = cmk(re, im);
        }
    chol_step<0>(NT); chol_step<1>(NT); chol_step<2>(NT); chol_step<3>(NT);
    chol_step<4>(NT); chol_step<5>(NT); chol_step<6>(NT); chol_step<7>(NT);

    cplx yv[8];
    #pragma unroll
    for (int r = 0; r < 8; r++) {
        cplx acc = u[r];
        #pragma unroll
        for (int k = 0; k < 8; k++) if (k < r) acc = csub(acc, cmul(NT[LT(r,k)], yv[k]));
        float inv = 1.f/NT[LT(r,r)].x;
        yv[r] = cmk(acc.x*inv, acc.y*inv);
    }
    cplx zv[8];
    #pragma unroll
    for (int r = 7; r >= 0; r--) {
        cplx acc = yv[r];
        #pragma unroll
        for (int k = 7; k >= 0; k--) if (k > r) acc = csub(acc, cmul(conjc(NT[LT(k,r)]), zv[k]));
        float inv = 1.f/NT[LT(r,r)].x;
        zv[r] = cmk(acc.x*inv, acc.y*inv);
    }
    cplx den = cmk(0.f, 0.f);
    #pragma unroll
    for (int m3 = 0; m3 < 8; m3++) den = cadd(den, cmul(conjc(u[m3]), zv[m3]));
    float dn = den.x*den.x + den.y*den.y;
    #pragma unroll
    for (int m3 = 0; m3 < 8; m3++) {
        float bfr = (zv[m3].x*den.x + zv[m3].y*den.y)/dn;
        float bfi = (zv[m3].y*den.x - zv[m3].x*den.y)/dn;
        ws[WS_W(2*m3)   + gid] = bfr;
        ws[WS_W(2*m3+1) + gid] = -bfi;
    }
}

// ============ apply (r12 green version; plateau ~95us @ ~3 TB/s) ============
__global__ __launch_bounds__(256) void mvdr_apply(
    const float* __restrict__ mix_re, const float* __restrict__ mix_im,
    const float* __restrict__ ws, float* __restrict__ out)
{
    const int bf = blockIdx.y;
    const int t = blockIdx.x*256 + threadIdx.x;
    const int b = bf >> 9, freq = bf & 511;
    if (t >= 1000) return;

    const size_t base = (((size_t)b*8)*512 + freq)*1000 + t;
    float xr[8], xi[8], wr[8], wi[8];
    #pragma unroll
    for (int m3 = 0; m3 < 8; m3++) {
        size_t idx = base + (size_t)m3*512*1000;
        xr[m3] = mix_re[idx];
        xi[m3] = mix_im[idx];
    }
    #pragma unroll
    for (int m3 = 0; m3 < 8; m3++) {
        wr[m3] = ws[WS_W(2*m3)   + bf];
        wi[m3] = ws[WS_W(2*m3+1) + bf];
    }
    float yr = 0.f;
    #pragma unroll
    for (int m3 = 0; m3 < 8; m3++)
        yr += wr[m3]*xr[m3] - wi[m3]*xi[m3];
    out[(size_t)bf*1000 + t] = yr;
}

extern "C" void kernel_launch(void* const* d_in, const int* in_sizes, int n_in,
                              void* d_out, int out_size, void* d_ws, size_t ws_size,
                              hipStream_t stream)
{
    (void)in_sizes; (void)n_in; (void)out_size;
    const float* mix_re = (const float*)d_in[0];
    const float* mix_im = (const float*)d_in[1];
    const float* ts_re  = (const float*)d_in[2];
    const float* ts_im  = (const float*)d_in[3];
    const float* ns_re  = (const float*)d_in[4];
    const float* ns_im  = (const float*)d_in[5];
    float* ws = (float*)d_ws;

    const size_t needed = (size_t)WS_PLANES * NBIN * sizeof(float);  // ~1.49 MB
    if (ws_size >= needed) {
        k1_tridiag_grp<<<dim3(NBIN/8), dim3(64), 0, stream>>>(ts_re, ts_im, ws);
        k2_steqr<<<dim3(NBIN), dim3(64), 0, stream>>>(ws);
        k3_solve_grp<<<dim3(NBIN/8), dim3(64), 0, stream>>>(ns_re, ns_im, ws);
    } else {
        k1_tridiag_slow<<<dim3(NBIN/64), dim3(64), 0, stream>>>(ts_re, ts_im, ws);
        k2_steqr<<<dim3(NBIN), dim3(64), 0, stream>>>(ws);
        k3_solve_slow<<<dim3(NBIN/64), dim3(64), 0, stream>>>(ts_re, ts_im, ns_re, ns_im, ws);
    }
    mvdr_apply<<<dim3(4, NBIN), dim3(256), 0, stream>>>(mix_re, mix_im, ws, (float*)d_out);
}